// Round 12
// baseline (107.952 us; speedup 1.0000x reference)
//
#include <hip/hip_runtime.h>
#include <hip/hip_bf16.h>

// ---------- problem constants ----------
constexpr int Bb   = 2;
constexpr int Ss   = 2048;
constexpr int Dm   = 1024;
constexpr int Hh   = 16;
constexpr int Hd   = 64;
constexpr int Mtot = Bb * Ss;      // 4096
constexpr int NCH  = Ss / 64;      // 32 chunks of 64

typedef __bf16 bf16x8 __attribute__((ext_vector_type(8)));
typedef float  f32x4  __attribute__((ext_vector_type(4)));
typedef __attribute__((address_space(1))) unsigned int u32_as1;
typedef __attribute__((address_space(3))) unsigned int u32_as3;

__device__ __forceinline__ void gload_lds16(const void* g, void* l) {
  __builtin_amdgcn_global_load_lds((const u32_as1*)g, (u32_as3*)l, 16, 0, 0);
}

__device__ __forceinline__ unsigned short f2bf(float f) {
  union { float f; unsigned u; } x; x.f = f;
  unsigned r = x.u + 0x7fffu + ((x.u >> 16) & 1u);   // RNE
  return (unsigned short)(r >> 16);
}

__device__ __forceinline__ float bf2f(unsigned short s) {
  union { unsigned u; float f; } x; x.u = ((unsigned)s) << 16;
  return x.f;
}

// ---------- fused prep: n-projection + x->bf16 + all three weight transposes ----------
__global__ __launch_bounds__(256) void k_prep(
    const float* __restrict__ x, const float* __restrict__ Wn, const float* __restrict__ bn,
    float* __restrict__ invn, unsigned short* __restrict__ xb,
    const float* __restrict__ Wqk, const float* __restrict__ Wv, const float* __restrict__ Wo,
    unsigned short* __restrict__ wprojT, unsigned short* __restrict__ woT) {
  __shared__ __align__(16) char smem[16384];
  int bi = blockIdx.x;
  int tid = threadIdx.x;
  if (bi < 1024) {
    float (*xl)[1024] = (float(*)[1024])smem;
    int w = tid >> 6, lane = tid & 63;
    int row = bi * 4 + w;                       // [0, 4096)
    const float4* x4 = (const float4*)(x + (size_t)row * Dm);
    ushort4* xb4 = (ushort4*)(xb + (size_t)row * Dm);
#pragma unroll
    for (int j = 0; j < 4; ++j) {
      float4 v = x4[j * 64 + lane];
      *(float4*)&xl[w][(j * 64 + lane) * 4] = v;
      ushort4 o;
      o.x = f2bf(v.x); o.y = f2bf(v.y); o.z = f2bf(v.z); o.w = f2bf(v.w);
      xb4[j * 64 + lane] = o;
    }
    __syncthreads();
    const float4* Wn4 = (const float4*)Wn;
    f32x4 sum = {0.f, 0.f, 0.f, 0.f};
#pragma unroll 4
    for (int j = 0; j < 64; ++j) {
      float xv = xl[w][j * 16 + (lane >> 2)];
      float4 wv = Wn4[j * 64 + lane];
      sum[0] += xv * wv.x; sum[1] += xv * wv.y; sum[2] += xv * wv.z; sum[3] += xv * wv.w;
    }
#pragma unroll
    for (int m = 4; m < 64; m <<= 1) {
      sum[0] += __shfl_xor(sum[0], m);
      sum[1] += __shfl_xor(sum[1], m);
      sum[2] += __shfl_xor(sum[2], m);
      sum[3] += __shfl_xor(sum[3], m);
    }
    if (lane < 4) {
      int b = row >> 11, s = row & 2047;
#pragma unroll
      for (int e = 0; e < 4; ++e) {
        int h = lane * 4 + e;
        float nv = sum[e] + bn[h];
        invn[((size_t)(b * Hh + h)) * Ss + s] = expf(-nv);
      }
    }
  } else {
    float (*t)[33] = (float(*)[33])smem;
    int ti = bi - 1024;
    const float* W; unsigned short* Wt; int N, n0, k0;
    if (ti < 2048) {
      W = Wqk; Wt = wprojT; N = 2048;
      n0 = (ti & 63) * 32; k0 = (ti >> 6) * 32;
    } else if (ti < 3072) {
      int l = ti - 2048; W = Wv; Wt = wprojT + (size_t)2048 * 1024; N = 1024;
      n0 = (l & 31) * 32; k0 = (l >> 5) * 32;
    } else {
      int l = ti - 3072; W = Wo; Wt = woT; N = 1024;
      n0 = (l & 31) * 32; k0 = (l >> 5) * 32;
    }
    int tx = tid & 31, ty = tid >> 5;
#pragma unroll
    for (int j = 0; j < 32; j += 8)
      t[ty + j][tx] = W[(size_t)(k0 + ty + j) * N + n0 + tx];
    __syncthreads();
#pragma unroll
    for (int j = 0; j < 32; j += 8)
      Wt[(size_t)(n0 + ty + j) * 1024 + k0 + tx] = f2bf(t[tx][ty + j]);
  }
}

// ---------- projection GEMM: 256x256 tile, BK=64, 8 waves, counted-vmcnt 4-phase pipeline ----------
// LDS per buf (64KB): A ks-major [ks][256 rows][64B] at 0, B at +32768. 2 bufs = 128 KB.
// Per K-tile: 4 phases; each phase issues 2 gload_lds (1 A + 1 B chunk part) and 16 MFMA.
// vmcnt(4) at end of phases 1 & 3 only (per-wave ledger: 8 outstanding, oldest 4 = chunk needed next).
// LDS swizzle: phys colb = logical colb ^ ((row&3)<<4) on both stage-source and read (involution).
// Epilogue: N=3072 scatter -> q [bh,t,d] / k [bh,t,d] + kT [bh,d,t] / vT [bh,d,t].
__global__ __launch_bounds__(512, 2) void k_gemm_proj8(
    const unsigned short* __restrict__ A, const unsigned short* __restrict__ BT,
    const float* __restrict__ bias0, const float* __restrict__ bias1,
    void* __restrict__ out0, void* __restrict__ out1, void* __restrict__ out2,
    void* __restrict__ out3) {
  constexpr int K = 1024, NT = 16;
  __shared__ __align__(16) char lds[131072];
  int tid = threadIdx.x, w = tid >> 6, lane = tid & 63;
  int wm = w >> 2, wn = w & 3;                 // 2M x 4N waves; wave tile 128x64

  // grid 12 x 16 = 192 blocks; bijective XCD swizzle, m-chunked (1 MB A-slice per XCD)
  int bid = blockIdx.y * gridDim.x + blockIdx.x;   // 0..191
  int swz = (bid & 7) * 24 + (bid >> 3);
  int by = swz / 12, bx = swz % 12;
  int m0 = by * 256, n0 = bx * 256;

  // per-thread staging constants: lane's data for part i lands at intra-region byte
  // d = i*8192 + w*1024 + lane*16 -> row r = d>>6, phys colb = d&63; logical colb = phys ^ ((r&3)<<4)
  int d0 = w * 1024 + lane * 16;
  int r0 = d0 >> 6, lc0 = ((d0 & 63) ^ ((r0 & 3) << 4)) >> 1;   // elem col in [0,32)
  int r1 = r0 + 128;                                            // part 1: (r&3) same -> lc same
  // read-side swizzled col-byte (row&3 == lane&3 for all fragments)
  int cS = ((lane >> 4) << 4) ^ ((lane & 3) << 4);
  int rA = (lane & 15);                        // fragment row low bits

  f32x4 acc[8][4] = {};

  auto STG = [&](int buf, int kt, int ks, int i) {
    int rr = i ? r1 : r0;
    int gc = kt * 64 + ks * 32 + lc0;
    char* db = lds + buf * 65536 + ks * 16384 + i * 8192 + w * 1024;   // wave-uniform dest
    gload_lds16(A  + (size_t)(m0 + rr) * K + gc, db);
    gload_lds16(BT + (size_t)(n0 + rr) * K + gc, db + 32768);
  };

  // prologue: stage tile 0 (c0 = ks0, then c1 = ks1) into buf 0; wait for c0 only
  STG(0, 0, 0, 0); STG(0, 0, 0, 1);
  STG(0, 0, 1, 0); STG(0, 0, 1, 1);
  asm volatile("s_waitcnt vmcnt(4)" ::: "memory");
  __builtin_amdgcn_s_barrier();
  asm volatile("" ::: "memory");

  for (int t = 0; t < NT; ++t) {
    int buf = t & 1, sb = buf ^ 1;
    int tn = (t + 1 < NT) ? t + 1 : t;         // last-tile re-stage: harmless, keeps ledger uniform
    const char* Lb = lds + buf * 65536;
    bf16x8 af[4], bfr[4];

#pragma unroll
    for (int ks = 0; ks < 2; ++ks) {
      const char* La = Lb + ks * 16384;
      const char* Bv = Lb + 32768 + ks * 16384;
      // ---- phase ks*2+0: bfr[0-3](ks) + af m0-3 ----
#pragma unroll
      for (int nf = 0; nf < 4; ++nf)
        bfr[nf] = *(const bf16x8*)(Bv + (wn * 64 + nf * 16 + rA) * 64 + cS);
#pragma unroll
      for (int mf = 0; mf < 4; ++mf)
        af[mf] = *(const bf16x8*)(La + (wm * 128 + mf * 16 + rA) * 64 + cS);
      STG(sb, tn, ks, 0);
      asm volatile("" ::: "memory");
      __builtin_amdgcn_s_barrier();
      __builtin_amdgcn_s_setprio(1);
#pragma unroll
      for (int mf = 0; mf < 4; ++mf)
#pragma unroll
        for (int nf = 0; nf < 4; ++nf)
          acc[mf][nf] = __builtin_amdgcn_mfma_f32_16x16x32_bf16(af[mf], bfr[nf], acc[mf][nf], 0, 0, 0);
      __builtin_amdgcn_s_setprio(0);
      __builtin_amdgcn_sched_barrier(0);
      asm volatile("" ::: "memory");
      __builtin_amdgcn_s_barrier();

      // ---- phase ks*2+1: af m4-7 (bfr reused) ----
#pragma unroll
      for (int mf = 0; mf < 4; ++mf)
        af[mf] = *(const bf16x8*)(La + (wm * 128 + (mf + 4) * 16 + rA) * 64 + cS);
      STG(sb, tn, ks, 1);
      asm volatile("" ::: "memory");
      __builtin_amdgcn_s_barrier();
      __builtin_amdgcn_s_setprio(1);
#pragma unroll
      for (int mf = 0; mf < 4; ++mf)
#pragma unroll
        for (int nf = 0; nf < 4; ++nf)
          acc[mf + 4][nf] = __builtin_amdgcn_mfma_f32_16x16x32_bf16(af[mf], bfr[nf], acc[mf + 4][nf], 0, 0, 0);
      __builtin_amdgcn_s_setprio(0);
      __builtin_amdgcn_sched_barrier(0);
      // counted wait: oldest 4 outstanding = the chunk read in the NEXT phase pair
      asm volatile("s_waitcnt vmcnt(4)" ::: "memory");
      __builtin_amdgcn_s_barrier();
      asm volatile("" ::: "memory");
    }
  }
  asm volatile("s_waitcnt vmcnt(0) lgkmcnt(0)" ::: "memory");

  // ---- epilogue scatter ----
#pragma unroll
  for (int mf = 0; mf < 8; ++mf) {
#pragma unroll
    for (int nf = 0; nf < 4; ++nf) {
      int n = n0 + wn * 64 + nf * 16 + (lane & 15);
      int tbase = m0 + wm * 128 + mf * 16 + (lane >> 4) * 4;
      int region = n >> 10;                 // block-uniform (n0 % 1024 in {0,256,512,768})
      int h = (n >> 6) & 15, d = n & 63;
      int b = tbase >> 11, t = tbase & 2047;
      float bb = (region < 2) ? bias0[n] : bias1[n - 2048];
      if (region == 0) {
        unsigned short* qp = (unsigned short*)out0;
#pragma unroll
        for (int r = 0; r < 4; ++r)
          qp[(((size_t)(b * Hh + h)) * Ss + t + r) * Hd + d] = f2bf(acc[mf][nf][r] + bb);
      } else if (region == 1) {
        unsigned short* kp = (unsigned short*)out1;
#pragma unroll
        for (int r = 0; r < 4; ++r)
          kp[(((size_t)(b * Hh + h)) * Ss + t + r) * Hd + d] = f2bf(acc[mf][nf][r] + bb);
        ushort4 o;
        o.x = f2bf(acc[mf][nf][0] + bb);
        o.y = f2bf(acc[mf][nf][1] + bb);
        o.z = f2bf(acc[mf][nf][2] + bb);
        o.w = f2bf(acc[mf][nf][3] + bb);
        *(ushort4*)((unsigned short*)out2 + ((size_t)(b * Hh + h) * Hd + d) * Ss + t) = o;
      } else {
        ushort4 o;
        o.x = f2bf(acc[mf][nf][0] + bb);
        o.y = f2bf(acc[mf][nf][1] + bb);
        o.z = f2bf(acc[mf][nf][2] + bb);
        o.w = f2bf(acc[mf][nf][3] + bb);
        *(ushort4*)((unsigned short*)out3 + ((size_t)(b * Hh + h) * Hd + d) * Ss + t) = o;
      }
    }
  }
}

// ---------- output GEMM: 64x128 tile, 2-phase dbuf + XCD swizzle (round-11 proven) ----------
__global__ __launch_bounds__(256, 3) void k_gemm_o(
    const unsigned short* __restrict__ A, const unsigned short* __restrict__ BT,
    const float* __restrict__ bias, float* __restrict__ out) {
  constexpr int K = 1024, N = 1024;
  __shared__ __align__(16) unsigned short As[2][64 * 64];
  __shared__ __align__(16) unsigned short Bs[2][128 * 64];
  int tid = threadIdx.x, w = tid >> 6, lane = tid & 63;
  int bid = blockIdx.y * gridDim.x + blockIdx.x;   // 0..511
  int xcd = bid & 7, idx = bid >> 3;               // 0..63
  int m0 = (xcd * 8 + (idx & 7)) * 64;
  int n0 = (idx >> 3) * 128;
  int wm = w >> 1, wn = w & 1;
  f32x4 acc[2][4] = {};

  auto STAGE = [&](int kt, int cur) {
#pragma unroll
    for (int i = 0; i < 2; ++i) {
      int lin = i * 2048 + w * 512 + lane * 8;
      int r = lin >> 6, c = lin & 63;
      gload_lds16(A + (size_t)(m0 + r) * K + kt * 64 + c, As[cur] + i * 2048 + w * 512);
    }
#pragma unroll
    for (int i = 0; i < 4; ++i) {
      int lin = i * 2048 + w * 512 + lane * 8;
      int r = lin >> 6, c = lin & 63;
      gload_lds16(BT + (size_t)(n0 + r) * K + kt * 64 + c, Bs[cur] + i * 2048 + w * 512);
    }
  };

  constexpr int NT = K >> 6;
  STAGE(0, 0);
  __syncthreads();
  for (int kt = 0; kt < NT; ++kt) {
    int cur = kt & 1;
    if (kt + 1 < NT) STAGE(kt + 1, cur ^ 1);
#pragma unroll
    for (int ks = 0; ks < 2; ++ks) {
      bf16x8 af[2], bfr[4];
#pragma unroll
      for (int mt = 0; mt < 2; ++mt)
        af[mt] = *(const bf16x8*)(As[cur] + (wm * 32 + mt * 16 + (lane & 15)) * 64 + ks * 32 + (lane >> 4) * 8);
#pragma unroll
      for (int nt = 0; nt < 4; ++nt)
        bfr[nt] = *(const bf16x8*)(Bs[cur] + (wn * 64 + nt * 16 + (lane & 15)) * 64 + ks * 32 + (lane >> 4) * 8);
#pragma unroll
      for (int mt = 0; mt < 2; ++mt)
#pragma unroll
        for (int nt = 0; nt < 4; ++nt)
          acc[mt][nt] = __builtin_amdgcn_mfma_f32_16x16x32_bf16(af[mt], bfr[nt], acc[mt][nt], 0, 0, 0);
    }
    __syncthreads();
  }

#pragma unroll
  for (int mt = 0; mt < 2; ++mt) {
#pragma unroll
    for (int nt = 0; nt < 4; ++nt) {
      int n = n0 + wn * 64 + nt * 16 + (lane & 15);
      int m = m0 + wm * 32 + mt * 16 + (lane >> 4) * 4;
      float bb = bias[n];
#pragma unroll
      for (int r = 0; r < 4; ++r)
        out[(size_t)(m + r) * N + n] = acc[mt][nt][r] + bb;
    }
  }
}

// ---------- pass A1: per-chunk gram ----------
__global__ __launch_bounds__(64) void k_gram(
    const unsigned short* __restrict__ vT, const unsigned short* __restrict__ kT,
    unsigned short* __restrict__ G) {
  int lane = threadIdx.x;
  int j = blockIdx.x, bh = blockIdx.y;
  int t0 = j * 64;
  const unsigned short* vb = vT + (size_t)bh * Hd * Ss;
  const unsigned short* kb = kT + (size_t)bh * Hd * Ss;
  unsigned short* g = G + ((size_t)bh * NCH + j) * 4096;

  bf16x8 af[4][2], bfr[4][2];
#pragma unroll
  for (int mt = 0; mt < 4; ++mt)
#pragma unroll
    for (int ks = 0; ks < 2; ++ks) {
      af[mt][ks]  = *(const bf16x8*)(vb + (size_t)(mt * 16 + (lane & 15)) * Ss + t0 + ks * 32 + (lane >> 4) * 8);
      bfr[mt][ks] = *(const bf16x8*)(kb + (size_t)(mt * 16 + (lane & 15)) * Ss + t0 + ks * 32 + (lane >> 4) * 8);
    }
  f32x4 acc[4][4] = {};
#pragma unroll
  for (int mt = 0; mt < 4; ++mt)
#pragma unroll
    for (int nt = 0; nt < 4; ++nt)
#pragma unroll
      for (int ks = 0; ks < 2; ++ks)
        acc[mt][nt] = __builtin_amdgcn_mfma_f32_16x16x32_bf16(af[mt][ks], bfr[nt][ks], acc[mt][nt], 0, 0, 0);
#pragma unroll
  for (int mt = 0; mt < 4; ++mt)
#pragma unroll
    for (int nt = 0; nt < 4; ++nt)
#pragma unroll
      for (int r = 0; r < 4; ++r)
        g[(mt * 16 + (lane >> 4) * 4 + r) * 64 + nt * 16 + (lane & 15)] = f2bf(acc[mt][nt][r]);
}

// ---------- pass A2: exclusive prefix over chunks ----------
__global__ __launch_bounds__(256) void k_prefix(
    const unsigned short* __restrict__ G, unsigned short* __restrict__ Sp) {
  int gidx = blockIdx.x * 256 + threadIdx.x;
  int bh = gidx >> 12, e = gidx & 4095;
  const unsigned short* gp = G + (size_t)bh * NCH * 4096 + e;
  unsigned short* sp = Sp + (size_t)bh * NCH * 4096 + e;
  float acc = 0.f;
#pragma unroll 8
  for (int j = 0; j < NCH; ++j) {
    sp[(size_t)j * 4096] = f2bf(acc);
    acc += bf2f(gp[(size_t)j * 4096]);
  }
}

// ---------- pass B: per-chunk attention ----------
__global__ __launch_bounds__(256, 6) void k_chunk_attn(
    const unsigned short* __restrict__ q, const unsigned short* __restrict__ k,
    const unsigned short* __restrict__ vT, const unsigned short* __restrict__ Sp,
    const float* __restrict__ invn, unsigned short* __restrict__ ctx) {
  __shared__ __align__(16) unsigned short P[4 * 16 * 64];
  int tid = threadIdx.x, w = tid >> 6, lane = tid & 63;
  int j = blockIdx.x, bh = blockIdx.y;
  int t0 = j * 64;
  const unsigned short* qb = q + (size_t)bh * Ss * Hd;
  const unsigned short* kb = k + (size_t)bh * Ss * Hd;
  const unsigned short* vb = vT + (size_t)bh * Hd * Ss;
  const unsigned short* sp = Sp + ((size_t)bh * NCH + j) * 4096;

  bf16x8 qf[2];
#pragma unroll
  for (int ks = 0; ks < 2; ++ks)
    qf[ks] = *(const bf16x8*)(qb + (size_t)(t0 + w * 16 + (lane & 15)) * Hd + ks * 32 + (lane >> 4) * 8);

  f32x4 acc[4] = {};
#pragma unroll
  for (int nt = 0; nt < 4; ++nt)
#pragma unroll
    for (int ks = 0; ks < 2; ++ks) {
      bf16x8 sf = *(const bf16x8*)(sp + (nt * 16 + (lane & 15)) * 64 + ks * 32 + (lane >> 4) * 8);
      acc[nt] = __builtin_amdgcn_mfma_f32_16x16x32_bf16(qf[ks], sf, acc[nt], 0, 0, 0);
    }

  f32x4 sacc[4] = {};
#pragma unroll
  for (int nt = 0; nt < 4; ++nt)
#pragma unroll
    for (int ks = 0; ks < 2; ++ks) {
      bf16x8 kf = *(const bf16x8*)(kb + (size_t)(t0 + nt * 16 + (lane & 15)) * Hd + ks * 32 + (lane >> 4) * 8);
      sacc[nt] = __builtin_amdgcn_mfma_f32_16x16x32_bf16(qf[ks], kf, sacc[nt], 0, 0, 0);
    }

#pragma unroll
  for (int nt = 0; nt < 4; ++nt)
#pragma unroll
    for (int r = 0; r < 4; ++r) {
      int row = (lane >> 4) * 4 + r;
      int s_local = nt * 16 + (lane & 15);
      float vv = (s_local <= w * 16 + row) ? sacc[nt][r] : 0.f;
      int cb = s_local * 2;
      int byte = w * 2048 + row * 128 + (cb ^ ((row & 7) << 4));
      *(unsigned short*)((char*)P + byte) = f2bf(vv);
    }
  asm volatile("" ::: "memory");

  bf16x8 pf[2];
#pragma unroll
  for (int ks = 0; ks < 2; ++ks) {
    int prow = lane & 15;
    int pcb = (ks * 32 + (lane >> 4) * 8) * 2;
    pf[ks] = *(const bf16x8*)((char*)P + w * 2048 + prow * 128 + (pcb ^ ((prow & 7) << 4)));
  }
#pragma unroll
  for (int dt = 0; dt < 4; ++dt)
#pragma unroll
    for (int ks = 0; ks < 2; ++ks) {
      bf16x8 vf = *(const bf16x8*)(vb + (size_t)(dt * 16 + (lane & 15)) * Ss + t0 + ks * 32 + (lane >> 4) * 8);
      acc[dt] = __builtin_amdgcn_mfma_f32_16x16x32_bf16(pf[ks], vf, acc[dt], 0, 0, 0);
    }

  int b = bh >> 4, h = bh & 15;
  float sc[4];
#pragma unroll
  for (int r = 0; r < 4; ++r)
    sc[r] = invn[(size_t)bh * Ss + t0 + w * 16 + (lane >> 4) * 4 + r];
#pragma unroll
  for (int dt = 0; dt < 4; ++dt)
#pragma unroll
    for (int r = 0; r < 4; ++r) {
      int t = t0 + w * 16 + (lane >> 4) * 4 + r;
      size_t m = (size_t)b * Ss + t;
      ctx[m * Dm + h * Hd + dt * 16 + (lane & 15)] = f2bf(acc[dt][r] * sc[r]);
    }
}

// ---------- launch ----------
extern "C" void kernel_launch(void* const* d_in, const int* in_sizes, int n_in,
                              void* d_out, int out_size, void* d_ws, size_t ws_size,
                              hipStream_t stream) {
  const float* x   = (const float*)d_in[0];
  const float* Wqk = (const float*)d_in[1];
  const float* bqk = (const float*)d_in[2];
  const float* Wv  = (const float*)d_in[3];
  const float* bv  = (const float*)d_in[4];
  const float* Wn  = (const float*)d_in[5];
  const float* bn  = (const float*)d_in[6];
  const float* Wo  = (const float*)d_in[7];
  const float* bo  = (const float*)d_in[8];

  char* ws = (char*)d_ws;
  size_t off = 0;
  unsigned short* xb    = (unsigned short*)(ws + off); off += (size_t)Mtot * Dm * 2;          // 8 MB
  unsigned short* wprojT= (unsigned short*)(ws + off); off += (size_t)3072 * 1024 * 2;        // 6 MB
  unsigned short* woT   = (unsigned short*)(ws + off); off += (size_t)1024 * 1024 * 2;        // 2 MB
  unsigned short* qbuf  = (unsigned short*)(ws + off); off += (size_t)Bb * Hh * Ss * Hd * 2;  // 8 MB
  unsigned short* kbuf  = (unsigned short*)(ws + off); off += (size_t)Bb * Hh * Ss * Hd * 2;  // 8 MB
  unsigned short* ktbuf = (unsigned short*)(ws + off); off += (size_t)Bb * Hh * Ss * Hd * 2;  // 8 MB
  unsigned short* vbuf  = (unsigned short*)(ws + off); off += (size_t)Bb * Hh * Ss * Hd * 2;  // 8 MB
  float* invn           = (float*)(ws + off);          off += (size_t)Bb * Hh * Ss * 4;       // 256 KB
  unsigned short* G     = (unsigned short*)(ws + off); off += (size_t)Bb * Hh * NCH * 4096 * 2; // 8 MB
  unsigned short* Sp    = (unsigned short*)(ws + off); off += (size_t)Bb * Hh * NCH * 4096 * 2; // 8 MB
  unsigned short* ctx   = xb;  // alias: xb dead after fused projection GEMM

  // 1) fused prep (one launch)
  k_prep<<<5120, 256, 0, stream>>>(x, Wn, bn, invn, xb, Wqk, Wv, Wo, wprojT, woT);

  // 2) fused q/k/v projections (N = 3072), 256x256 counted-vmcnt pipeline (192 blocks)
  k_gemm_proj8<<<dim3(3072 / 256, Mtot / 256), 512, 0, stream>>>(
      xb, wprojT, bqk, bv, qbuf, kbuf, ktbuf, vbuf);

  // 3) attention = parallel gram + parallel prefix + per-chunk
  k_gram<<<dim3(NCH, Bb * Hh), 64, 0, stream>>>(vbuf, ktbuf, G);
  k_prefix<<<(Bb * Hh * 4096) / 256, 256, 0, stream>>>(G, Sp);
  k_chunk_attn<<<dim3(NCH, Bb * Hh), 256, 0, stream>>>(qbuf, kbuf, vbuf, Sp, invn, ctx);

  // 4) output projection -> f32 d_out, 64x128 2-phase dbuf + XCD swizzle (512 blocks)
  k_gemm_o<<<dim3(1024 / 128, Mtot / 64), 256, 0, stream>>>(ctx, woT, bo, (float*)d_out);
}

// Round 13
// 106.259 us; speedup vs baseline: 1.0159x; 1.0159x over previous
//
#include <hip/hip_runtime.h>
#include <hip/hip_bf16.h>

// ---------- problem constants ----------
constexpr int Bb   = 2;
constexpr int Ss   = 2048;
constexpr int Dm   = 1024;
constexpr int Hh   = 16;
constexpr int Hd   = 64;
constexpr int Mtot = Bb * Ss;      // 4096
constexpr int NCH  = Ss / 64;      // 32 chunks of 64

typedef __bf16 bf16x8 __attribute__((ext_vector_type(8)));
typedef float  f32x4  __attribute__((ext_vector_type(4)));
typedef __attribute__((address_space(1))) unsigned int u32_as1;
typedef __attribute__((address_space(3))) unsigned int u32_as3;

__device__ __forceinline__ void gload_lds16(const void* g, void* l) {
  __builtin_amdgcn_global_load_lds((const u32_as1*)g, (u32_as3*)l, 16, 0, 0);
}

__device__ __forceinline__ unsigned short f2bf(float f) {
  union { float f; unsigned u; } x; x.f = f;
  unsigned r = x.u + 0x7fffu + ((x.u >> 16) & 1u);   // RNE
  return (unsigned short)(r >> 16);
}

__device__ __forceinline__ float bf2f(unsigned short s) {
  union { unsigned u; float f; } x; x.u = ((unsigned)s) << 16;
  return x.f;
}

// ---------- fused prep: n-projection + x->bf16 + all three weight transposes ----------
__global__ __launch_bounds__(256) void k_prep(
    const float* __restrict__ x, const float* __restrict__ Wn, const float* __restrict__ bn,
    float* __restrict__ invn, unsigned short* __restrict__ xb,
    const float* __restrict__ Wqk, const float* __restrict__ Wv, const float* __restrict__ Wo,
    unsigned short* __restrict__ wprojT, unsigned short* __restrict__ woT) {
  __shared__ __align__(16) char smem[16384];
  int bi = blockIdx.x;
  int tid = threadIdx.x;
  if (bi < 1024) {
    float (*xl)[1024] = (float(*)[1024])smem;
    int w = tid >> 6, lane = tid & 63;
    int row = bi * 4 + w;                       // [0, 4096)
    const float4* x4 = (const float4*)(x + (size_t)row * Dm);
    ushort4* xb4 = (ushort4*)(xb + (size_t)row * Dm);
#pragma unroll
    for (int j = 0; j < 4; ++j) {
      float4 v = x4[j * 64 + lane];
      *(float4*)&xl[w][(j * 64 + lane) * 4] = v;
      ushort4 o;
      o.x = f2bf(v.x); o.y = f2bf(v.y); o.z = f2bf(v.z); o.w = f2bf(v.w);
      xb4[j * 64 + lane] = o;
    }
    __syncthreads();
    const float4* Wn4 = (const float4*)Wn;
    f32x4 sum = {0.f, 0.f, 0.f, 0.f};
#pragma unroll 4
    for (int j = 0; j < 64; ++j) {
      float xv = xl[w][j * 16 + (lane >> 2)];
      float4 wv = Wn4[j * 64 + lane];
      sum[0] += xv * wv.x; sum[1] += xv * wv.y; sum[2] += xv * wv.z; sum[3] += xv * wv.w;
    }
#pragma unroll
    for (int m = 4; m < 64; m <<= 1) {
      sum[0] += __shfl_xor(sum[0], m);
      sum[1] += __shfl_xor(sum[1], m);
      sum[2] += __shfl_xor(sum[2], m);
      sum[3] += __shfl_xor(sum[3], m);
    }
    if (lane < 4) {
      int b = row >> 11, s = row & 2047;
#pragma unroll
      for (int e = 0; e < 4; ++e) {
        int h = lane * 4 + e;
        float nv = sum[e] + bn[h];
        invn[((size_t)(b * Hh + h)) * Ss + s] = expf(-nv);
      }
    }
  } else {
    float (*t)[33] = (float(*)[33])smem;
    int ti = bi - 1024;
    const float* W; unsigned short* Wt; int N, n0, k0;
    if (ti < 2048) {
      W = Wqk; Wt = wprojT; N = 2048;
      n0 = (ti & 63) * 32; k0 = (ti >> 6) * 32;
    } else if (ti < 3072) {
      int l = ti - 2048; W = Wv; Wt = wprojT + (size_t)2048 * 1024; N = 1024;
      n0 = (l & 31) * 32; k0 = (l >> 5) * 32;
    } else {
      int l = ti - 3072; W = Wo; Wt = woT; N = 1024;
      n0 = (l & 31) * 32; k0 = (l >> 5) * 32;
    }
    int tx = tid & 31, ty = tid >> 5;
#pragma unroll
    for (int j = 0; j < 32; j += 8)
      t[ty + j][tx] = W[(size_t)(k0 + ty + j) * N + n0 + tx];
    __syncthreads();
#pragma unroll
    for (int j = 0; j < 32; j += 8)
      Wt[(size_t)(n0 + ty + j) * 1024 + k0 + tx] = f2bf(t[tx][ty + j]);
  }
}

// ---------- fused projection GEMM (m97 structure + XCD swizzle, round-11 proven) ----------
// NEW: LDS-roundtrip epilogue for the q/k [bh][t][d] regions (replaces 2-byte scatter with
// 16B coalesced row stores). kT/vT writes unchanged (already ushort4, t-contiguous).
// N=3072: n<1024 -> q [bh,t,d]; 1024<=n<2048 -> k [bh,t,d] + kT [bh,d,t]; n>=2048 -> vT [bh,d,t]
__global__ __launch_bounds__(256, 4) void k_gemm_proj(
    const unsigned short* __restrict__ A, const unsigned short* __restrict__ BT,
    const float* __restrict__ bias0, const float* __restrict__ bias1,
    void* __restrict__ out0, void* __restrict__ out1, void* __restrict__ out2,
    void* __restrict__ out3, int M, int N, int K) {
  __shared__ __align__(16) unsigned short SMEM[2 * 128 * 64];   // 32 KB: As | Bs, reused by epilogue
  unsigned short* As = SMEM;
  unsigned short* Bs = SMEM + 128 * 64;
  int tid = threadIdx.x, w = tid >> 6, lane = tid & 63;
  // XCD swizzle: bid%8 -> XCD (dispatch round-robin); per-XCD: 4 m-blocks x 24 n-blocks
  int bid = blockIdx.y * gridDim.x + blockIdx.x;   // 0..767
  int xcd = bid & 7, idx = bid >> 3;               // idx 0..95
  int m0 = (xcd * 4 + (idx & 3)) * 128;
  int n0 = (idx >> 2) * 128;
  int wm = w >> 1, wn = w & 1;
  f32x4 acc[4][4] = {};

  for (int kt = 0; kt < (K >> 6); ++kt) {
#pragma unroll
    for (int i = 0; i < 4; ++i) {
      int lin = i * 2048 + w * 512 + lane * 8;
      int r = lin >> 6, c = lin & 63;
      gload_lds16(A + (size_t)(m0 + r) * K + kt * 64 + c, As + i * 2048 + w * 512);
    }
#pragma unroll
    for (int i = 0; i < 4; ++i) {
      int lin = i * 2048 + w * 512 + lane * 8;
      int r = lin >> 6, c = lin & 63;
      gload_lds16(BT + (size_t)(n0 + r) * K + kt * 64 + c, Bs + i * 2048 + w * 512);
    }
    __syncthreads();
#pragma unroll
    for (int ks = 0; ks < 2; ++ks) {
      bf16x8 af[4], bfr[4];
#pragma unroll
      for (int mt = 0; mt < 4; ++mt)
        af[mt] = *(const bf16x8*)(As + (wm * 64 + mt * 16 + (lane & 15)) * 64 + ks * 32 + (lane >> 4) * 8);
#pragma unroll
      for (int nt = 0; nt < 4; ++nt)
        bfr[nt] = *(const bf16x8*)(Bs + (wn * 64 + nt * 16 + (lane & 15)) * 64 + ks * 32 + (lane >> 4) * 8);
#pragma unroll
      for (int mt = 0; mt < 4; ++mt)
#pragma unroll
        for (int nt = 0; nt < 4; ++nt)
          acc[mt][nt] = __builtin_amdgcn_mfma_f32_16x16x32_bf16(af[mt], bfr[nt], acc[mt][nt], 0, 0, 0);
    }
    __syncthreads();   // after this in the last iter, SMEM is dead -> epilogue may reuse
  }

  // ---- epilogue ----
  int nfirst = n0 + wn * 64;                 // wave's 64-wide n-range start (mult of 64)
  int region = nfirst >> 10;                 // wave-uniform
  unsigned short* eplds = SMEM + w * 4096;   // per-wave 64x64 ushort slice (8 KB)

#pragma unroll
  for (int mt = 0; mt < 4; ++mt) {
#pragma unroll
    for (int nt = 0; nt < 4; ++nt) {
      int n = nfirst + nt * 16 + (lane & 15);
      int tbase = m0 + wm * 64 + mt * 16 + (lane >> 4) * 4;
      float bb = (region < 2) ? bias0[n] : bias1[n - 2048];
      if (region <= 1) {
        // stage the [t][d] patch into LDS (XOR-swizzled cols, per-wave slice)
#pragma unroll
        for (int r = 0; r < 4; ++r) {
          int tl = mt * 16 + (lane >> 4) * 4 + r;          // 0..63 (row in patch)
          int col = nt * 16 + (lane & 15);                 // 0..63 (= d)
          eplds[tl * 64 + (col ^ ((tl & 7) << 3))] = f2bf(acc[mt][nt][r] + bb);
        }
        if (region == 1) {  // kT [bh][d][t] direct (t-contiguous)
          int h = (n >> 6) & 15, d = n & 63, b = tbase >> 11, t = tbase & 2047;
          ushort4 o;
          o.x = f2bf(acc[mt][nt][0] + bb);
          o.y = f2bf(acc[mt][nt][1] + bb);
          o.z = f2bf(acc[mt][nt][2] + bb);
          o.w = f2bf(acc[mt][nt][3] + bb);
          *(ushort4*)((unsigned short*)out2 + ((size_t)(b * Hh + h) * Hd + d) * Ss + t) = o;
        }
      } else {            // vT [bh][d][t] direct
        int h = (n >> 6) & 15, d = n & 63, b = tbase >> 11, t = tbase & 2047;
        ushort4 o;
        o.x = f2bf(acc[mt][nt][0] + bb);
        o.y = f2bf(acc[mt][nt][1] + bb);
        o.z = f2bf(acc[mt][nt][2] + bb);
        o.w = f2bf(acc[mt][nt][3] + bb);
        *(ushort4*)((unsigned short*)out3 + ((size_t)(b * Hh + h) * Hd + d) * Ss + t) = o;
      }
    }
  }
  if (region <= 1) {
    asm volatile("" ::: "memory");           // order LDS reads after writes (wave-private slice)
    int tl = lane;                           // one 128B row per lane
    int tt = m0 + wm * 64 + tl;
    int b = tt >> 11, t = tt & 2047;
    int h = (nfirst >> 6) & 15;
    unsigned short* dst = ((region == 0) ? (unsigned short*)out0 : (unsigned short*)out1)
                        + (((size_t)(b * Hh + h)) * Ss + t) * Hd;
#pragma unroll
    for (int c = 0; c < 8; ++c) {
      int col = (c * 8) ^ ((tl & 7) << 3);
      *(float4*)(dst + c * 8) = *(const float4*)(eplds + tl * 64 + col);
    }
  }
}

// ---------- output GEMM: 64x128 tile, 2-phase dbuf + XCD swizzle (round-11 proven) ----------
__global__ __launch_bounds__(256, 3) void k_gemm_o(
    const unsigned short* __restrict__ A, const unsigned short* __restrict__ BT,
    const float* __restrict__ bias, float* __restrict__ out) {
  constexpr int K = 1024, N = 1024;
  __shared__ __align__(16) unsigned short As[2][64 * 64];
  __shared__ __align__(16) unsigned short Bs[2][128 * 64];
  int tid = threadIdx.x, w = tid >> 6, lane = tid & 63;
  int bid = blockIdx.y * gridDim.x + blockIdx.x;   // 0..511
  int xcd = bid & 7, idx = bid >> 3;               // 0..63
  int m0 = (xcd * 8 + (idx & 7)) * 64;
  int n0 = (idx >> 3) * 128;
  int wm = w >> 1, wn = w & 1;
  f32x4 acc[2][4] = {};

  auto STAGE = [&](int kt, int cur) {
#pragma unroll
    for (int i = 0; i < 2; ++i) {
      int lin = i * 2048 + w * 512 + lane * 8;
      int r = lin >> 6, c = lin & 63;
      gload_lds16(A + (size_t)(m0 + r) * K + kt * 64 + c, As[cur] + i * 2048 + w * 512);
    }
#pragma unroll
    for (int i = 0; i < 4; ++i) {
      int lin = i * 2048 + w * 512 + lane * 8;
      int r = lin >> 6, c = lin & 63;
      gload_lds16(BT + (size_t)(n0 + r) * K + kt * 64 + c, Bs[cur] + i * 2048 + w * 512);
    }
  };

  constexpr int NT = K >> 6;
  STAGE(0, 0);
  __syncthreads();
  for (int kt = 0; kt < NT; ++kt) {
    int cur = kt & 1;
    if (kt + 1 < NT) STAGE(kt + 1, cur ^ 1);
#pragma unroll
    for (int ks = 0; ks < 2; ++ks) {
      bf16x8 af[2], bfr[4];
#pragma unroll
      for (int mt = 0; mt < 2; ++mt)
        af[mt] = *(const bf16x8*)(As[cur] + (wm * 32 + mt * 16 + (lane & 15)) * 64 + ks * 32 + (lane >> 4) * 8);
#pragma unroll
      for (int nt = 0; nt < 4; ++nt)
        bfr[nt] = *(const bf16x8*)(Bs[cur] + (wn * 64 + nt * 16 + (lane & 15)) * 64 + ks * 32 + (lane >> 4) * 8);
#pragma unroll
      for (int mt = 0; mt < 2; ++mt)
#pragma unroll
        for (int nt = 0; nt < 4; ++nt)
          acc[mt][nt] = __builtin_amdgcn_mfma_f32_16x16x32_bf16(af[mt], bfr[nt], acc[mt][nt], 0, 0, 0);
    }
    __syncthreads();
  }

#pragma unroll
  for (int mt = 0; mt < 2; ++mt) {
#pragma unroll
    for (int nt = 0; nt < 4; ++nt) {
      int n = n0 + wn * 64 + nt * 16 + (lane & 15);
      int m = m0 + wm * 32 + mt * 16 + (lane >> 4) * 4;
      float bb = bias[n];
#pragma unroll
      for (int r = 0; r < 4; ++r)
        out[(size_t)(m + r) * N + n] = acc[mt][nt][r] + bb;
    }
  }
}

// ---------- pass A1: per-chunk gram ----------
__global__ __launch_bounds__(64) void k_gram(
    const unsigned short* __restrict__ vT, const unsigned short* __restrict__ kT,
    unsigned short* __restrict__ G) {
  int lane = threadIdx.x;
  int j = blockIdx.x, bh = blockIdx.y;
  int t0 = j * 64;
  const unsigned short* vb = vT + (size_t)bh * Hd * Ss;
  const unsigned short* kb = kT + (size_t)bh * Hd * Ss;
  unsigned short* g = G + ((size_t)bh * NCH + j) * 4096;

  bf16x8 af[4][2], bfr[4][2];
#pragma unroll
  for (int mt = 0; mt < 4; ++mt)
#pragma unroll
    for (int ks = 0; ks < 2; ++ks) {
      af[mt][ks]  = *(const bf16x8*)(vb + (size_t)(mt * 16 + (lane & 15)) * Ss + t0 + ks * 32 + (lane >> 4) * 8);
      bfr[mt][ks] = *(const bf16x8*)(kb + (size_t)(mt * 16 + (lane & 15)) * Ss + t0 + ks * 32 + (lane >> 4) * 8);
    }
  f32x4 acc[4][4] = {};
#pragma unroll
  for (int mt = 0; mt < 4; ++mt)
#pragma unroll
    for (int nt = 0; nt < 4; ++nt)
#pragma unroll
      for (int ks = 0; ks < 2; ++ks)
        acc[mt][nt] = __builtin_amdgcn_mfma_f32_16x16x32_bf16(af[mt][ks], bfr[nt][ks], acc[mt][nt], 0, 0, 0);
#pragma unroll
  for (int mt = 0; mt < 4; ++mt)
#pragma unroll
    for (int nt = 0; nt < 4; ++nt)
#pragma unroll
      for (int r = 0; r < 4; ++r)
        g[(mt * 16 + (lane >> 4) * 4 + r) * 64 + nt * 16 + (lane & 15)] = f2bf(acc[mt][nt][r]);
}

// ---------- pass A2: exclusive prefix over chunks (fully unrolled -> 32 loads in flight) ----------
__global__ __launch_bounds__(256) void k_prefix(
    const unsigned short* __restrict__ G, unsigned short* __restrict__ Sp) {
  int gidx = blockIdx.x * 256 + threadIdx.x;   // 32 bh * 4096 elems
  int bh = gidx >> 12, e = gidx & 4095;
  const unsigned short* gp = G + (size_t)bh * NCH * 4096 + e;
  unsigned short* sp = Sp + (size_t)bh * NCH * 4096 + e;
  float acc = 0.f;
#pragma unroll
  for (int j = 0; j < NCH; ++j) {
    sp[(size_t)j * 4096] = f2bf(acc);
    acc += bf2f(gp[(size_t)j * 4096]);
  }
}

// ---------- pass B: per-chunk attention ----------
__global__ __launch_bounds__(256, 6) void k_chunk_attn(
    const unsigned short* __restrict__ q, const unsigned short* __restrict__ k,
    const unsigned short* __restrict__ vT, const unsigned short* __restrict__ Sp,
    const float* __restrict__ invn, unsigned short* __restrict__ ctx) {
  __shared__ __align__(16) unsigned short P[4 * 16 * 64];
  int tid = threadIdx.x, w = tid >> 6, lane = tid & 63;
  int j = blockIdx.x, bh = blockIdx.y;
  int t0 = j * 64;
  const unsigned short* qb = q + (size_t)bh * Ss * Hd;
  const unsigned short* kb = k + (size_t)bh * Ss * Hd;
  const unsigned short* vb = vT + (size_t)bh * Hd * Ss;
  const unsigned short* sp = Sp + ((size_t)bh * NCH + j) * 4096;

  bf16x8 qf[2];
#pragma unroll
  for (int ks = 0; ks < 2; ++ks)
    qf[ks] = *(const bf16x8*)(qb + (size_t)(t0 + w * 16 + (lane & 15)) * Hd + ks * 32 + (lane >> 4) * 8);

  f32x4 acc[4] = {};
#pragma unroll
  for (int nt = 0; nt < 4; ++nt)
#pragma unroll
    for (int ks = 0; ks < 2; ++ks) {
      bf16x8 sf = *(const bf16x8*)(sp + (nt * 16 + (lane & 15)) * 64 + ks * 32 + (lane >> 4) * 8);
      acc[nt] = __builtin_amdgcn_mfma_f32_16x16x32_bf16(qf[ks], sf, acc[nt], 0, 0, 0);
    }

  f32x4 sacc[4] = {};
#pragma unroll
  for (int nt = 0; nt < 4; ++nt)
#pragma unroll
    for (int ks = 0; ks < 2; ++ks) {
      bf16x8 kf = *(const bf16x8*)(kb + (size_t)(t0 + nt * 16 + (lane & 15)) * Hd + ks * 32 + (lane >> 4) * 8);
      sacc[nt] = __builtin_amdgcn_mfma_f32_16x16x32_bf16(qf[ks], kf, sacc[nt], 0, 0, 0);
    }

#pragma unroll
  for (int nt = 0; nt < 4; ++nt)
#pragma unroll
    for (int r = 0; r < 4; ++r) {
      int row = (lane >> 4) * 4 + r;
      int s_local = nt * 16 + (lane & 15);
      float vv = (s_local <= w * 16 + row) ? sacc[nt][r] : 0.f;
      int cb = s_local * 2;
      int byte = w * 2048 + row * 128 + (cb ^ ((row & 7) << 4));
      *(unsigned short*)((char*)P + byte) = f2bf(vv);
    }
  asm volatile("" ::: "memory");

  bf16x8 pf[2];
#pragma unroll
  for (int ks = 0; ks < 2; ++ks) {
    int prow = lane & 15;
    int pcb = (ks * 32 + (lane >> 4) * 8) * 2;
    pf[ks] = *(const bf16x8*)((char*)P + w * 2048 + prow * 128 + (pcb ^ ((prow & 7) << 4)));
  }
#pragma unroll
  for (int dt = 0; dt < 4; ++dt)
#pragma unroll
    for (int ks = 0; ks < 2; ++ks) {
      bf16x8 vf = *(const bf16x8*)(vb + (size_t)(dt * 16 + (lane & 15)) * Ss + t0 + ks * 32 + (lane >> 4) * 8);
      acc[dt] = __builtin_amdgcn_mfma_f32_16x16x32_bf16(pf[ks], vf, acc[dt], 0, 0, 0);
    }

  int b = bh >> 4, h = bh & 15;
  float sc[4];
#pragma unroll
  for (int r = 0; r < 4; ++r)
    sc[r] = invn[(size_t)bh * Ss + t0 + w * 16 + (lane >> 4) * 4 + r];
#pragma unroll
  for (int dt = 0; dt < 4; ++dt)
#pragma unroll
    for (int r = 0; r < 4; ++r) {
      int t = t0 + w * 16 + (lane >> 4) * 4 + r;
      size_t m = (size_t)b * Ss + t;
      ctx[m * Dm + h * Hd + dt * 16 + (lane & 15)] = f2bf(acc[dt][r] * sc[r]);
    }
}

// ---------- launch ----------
extern "C" void kernel_launch(void* const* d_in, const int* in_sizes, int n_in,
                              void* d_out, int out_size, void* d_ws, size_t ws_size,
                              hipStream_t stream) {
  const float* x   = (const float*)d_in[0];
  const float* Wqk = (const float*)d_in[1];
  const float* bqk = (const float*)d_in[2];
  const float* Wv  = (const float*)d_in[3];
  const float* bv  = (const float*)d_in[4];
  const float* Wn  = (const float*)d_in[5];
  const float* bn  = (const float*)d_in[6];
  const float* Wo  = (const float*)d_in[7];
  const float* bo  = (const float*)d_in[8];

  char* ws = (char*)d_ws;
  size_t off = 0;
  unsigned short* xb    = (unsigned short*)(ws + off); off += (size_t)Mtot * Dm * 2;          // 8 MB
  unsigned short* wprojT= (unsigned short*)(ws + off); off += (size_t)3072 * 1024 * 2;        // 6 MB
  unsigned short* woT   = (unsigned short*)(ws + off); off += (size_t)1024 * 1024 * 2;        // 2 MB
  unsigned short* qbuf  = (unsigned short*)(ws + off); off += (size_t)Bb * Hh * Ss * Hd * 2;  // 8 MB
  unsigned short* kbuf  = (unsigned short*)(ws + off); off += (size_t)Bb * Hh * Ss * Hd * 2;  // 8 MB
  unsigned short* ktbuf = (unsigned short*)(ws + off); off += (size_t)Bb * Hh * Ss * Hd * 2;  // 8 MB
  unsigned short* vbuf  = (unsigned short*)(ws + off); off += (size_t)Bb * Hh * Ss * Hd * 2;  // 8 MB
  float* invn           = (float*)(ws + off);          off += (size_t)Bb * Hh * Ss * 4;       // 256 KB
  unsigned short* G     = (unsigned short*)(ws + off); off += (size_t)Bb * Hh * NCH * 4096 * 2; // 8 MB
  unsigned short* Sp    = (unsigned short*)(ws + off); off += (size_t)Bb * Hh * NCH * 4096 * 2; // 8 MB
  unsigned short* ctx   = xb;  // alias: xb dead after fused projection GEMM

  // 1) fused prep (one launch)
  k_prep<<<5120, 256, 0, stream>>>(x, Wn, bn, invn, xb, Wqk, Wv, Wo, wprojT, woT);

  // 2) fused q/k/v projections (N = 3072), m97 + XCD swizzle + LDS epilogue (768 blocks)
  k_gemm_proj<<<dim3(3072 / 128, Mtot / 128), 256, 0, stream>>>(
      xb, wprojT, bqk, bv, qbuf, kbuf, ktbuf, vbuf, Mtot, 3072, 1024);

  // 3) attention = parallel gram + parallel prefix + per-chunk
  k_gram<<<dim3(NCH, Bb * Hh), 64, 0, stream>>>(vbuf, ktbuf, G);
  k_prefix<<<(Bb * Hh * 4096) / 256, 256, 0, stream>>>(G, Sp);
  k_chunk_attn<<<dim3(NCH, Bb * Hh), 256, 0, stream>>>(qbuf, kbuf, vbuf, Sp, invn, ctx);

  // 4) output projection -> f32 d_out, 64x128 2-phase dbuf + XCD swizzle (512 blocks)
  k_gemm_o<<<dim3(1024 / 128, Mtot / 64), 256, 0, stream>>>(ctx, woT, bo, (float*)d_out);
}

// Round 14
// 100.991 us; speedup vs baseline: 1.0689x; 1.0522x over previous
//
#include <hip/hip_runtime.h>
#include <hip/hip_bf16.h>

// ---------- problem constants ----------
constexpr int Bb   = 2;
constexpr int Ss   = 2048;
constexpr int Dm   = 1024;
constexpr int Hh   = 16;
constexpr int Hd   = 64;
constexpr int Mtot = Bb * Ss;      // 4096
constexpr int NCH  = Ss / 64;      // 32 chunks of 64

typedef __bf16 bf16x8 __attribute__((ext_vector_type(8)));
typedef float  f32x4  __attribute__((ext_vector_type(4)));
typedef __attribute__((address_space(1))) unsigned int u32_as1;
typedef __attribute__((address_space(3))) unsigned int u32_as3;

__device__ __forceinline__ void gload_lds16(const void* g, void* l) {
  __builtin_amdgcn_global_load_lds((const u32_as1*)g, (u32_as3*)l, 16, 0, 0);
}

__device__ __forceinline__ unsigned short f2bf(float f) {
  union { float f; unsigned u; } x; x.f = f;
  unsigned r = x.u + 0x7fffu + ((x.u >> 16) & 1u);   // RNE
  return (unsigned short)(r >> 16);
}

__device__ __forceinline__ float bf2f(unsigned short s) {
  union { unsigned u; float f; } x; x.u = ((unsigned)s) << 16;
  return x.f;
}

// ---------- fused prep: n-projection + x->bf16 + all three weight transposes ----------
__global__ __launch_bounds__(256) void k_prep(
    const float* __restrict__ x, const float* __restrict__ Wn, const float* __restrict__ bn,
    float* __restrict__ invn, unsigned short* __restrict__ xb,
    const float* __restrict__ Wqk, const float* __restrict__ Wv, const float* __restrict__ Wo,
    unsigned short* __restrict__ wprojT, unsigned short* __restrict__ woT) {
  __shared__ __align__(16) char smem[16384];
  int bi = blockIdx.x;
  int tid = threadIdx.x;
  if (bi < 1024) {
    float (*xl)[1024] = (float(*)[1024])smem;
    int w = tid >> 6, lane = tid & 63;
    int row = bi * 4 + w;                       // [0, 4096)
    const float4* x4 = (const float4*)(x + (size_t)row * Dm);
    ushort4* xb4 = (ushort4*)(xb + (size_t)row * Dm);
#pragma unroll
    for (int j = 0; j < 4; ++j) {
      float4 v = x4[j * 64 + lane];
      *(float4*)&xl[w][(j * 64 + lane) * 4] = v;
      ushort4 o;
      o.x = f2bf(v.x); o.y = f2bf(v.y); o.z = f2bf(v.z); o.w = f2bf(v.w);
      xb4[j * 64 + lane] = o;
    }
    __syncthreads();
    const float4* Wn4 = (const float4*)Wn;
    f32x4 sum = {0.f, 0.f, 0.f, 0.f};
#pragma unroll 4
    for (int j = 0; j < 64; ++j) {
      float xv = xl[w][j * 16 + (lane >> 2)];
      float4 wv = Wn4[j * 64 + lane];
      sum[0] += xv * wv.x; sum[1] += xv * wv.y; sum[2] += xv * wv.z; sum[3] += xv * wv.w;
    }
#pragma unroll
    for (int m = 4; m < 64; m <<= 1) {
      sum[0] += __shfl_xor(sum[0], m);
      sum[1] += __shfl_xor(sum[1], m);
      sum[2] += __shfl_xor(sum[2], m);
      sum[3] += __shfl_xor(sum[3], m);
    }
    if (lane < 4) {
      int b = row >> 11, s = row & 2047;
#pragma unroll
      for (int e = 0; e < 4; ++e) {
        int h = lane * 4 + e;
        float nv = sum[e] + bn[h];
        invn[((size_t)(b * Hh + h)) * Ss + s] = expf(-nv);
      }
    }
  } else {
    float (*t)[33] = (float(*)[33])smem;
    int ti = bi - 1024;
    const float* W; unsigned short* Wt; int N, n0, k0;
    if (ti < 2048) {
      W = Wqk; Wt = wprojT; N = 2048;
      n0 = (ti & 63) * 32; k0 = (ti >> 6) * 32;
    } else if (ti < 3072) {
      int l = ti - 2048; W = Wv; Wt = wprojT + (size_t)2048 * 1024; N = 1024;
      n0 = (l & 31) * 32; k0 = (l >> 5) * 32;
    } else {
      int l = ti - 3072; W = Wo; Wt = woT; N = 1024;
      n0 = (l & 31) * 32; k0 = (l >> 5) * 32;
    }
    int tx = tid & 31, ty = tid >> 5;
#pragma unroll
    for (int j = 0; j < 32; j += 8)
      t[ty + j][tx] = W[(size_t)(k0 + ty + j) * N + n0 + tx];
    __syncthreads();
#pragma unroll
    for (int j = 0; j < 32; j += 8)
      Wt[(size_t)(n0 + ty + j) * 1024 + k0 + tx] = f2bf(t[tx][ty + j]);
  }
}

// ---------- fused projection GEMM (m97 structure + XCD swizzle + LDS epilogue) ----------
// NEW (T2): LDS tile layout elem(r,c) at byte r*128 + (c*2 ^ ((r&7)<<4)).
// Staging keeps linear gload_lds dest; the per-lane GLOBAL SOURCE column is pre-swizzled
// (rule 21: source permutation == read permutation, both the same involution).
// After swizzle each 16-lane ds_read_b128 group hits 8 distinct 16B slots -> 2-way (free).
// N=3072: n<1024 -> q [bh,t,d]; 1024<=n<2048 -> k [bh,t,d] + kT [bh,d,t]; n>=2048 -> vT [bh,d,t]
__global__ __launch_bounds__(256, 4) void k_gemm_proj(
    const unsigned short* __restrict__ A, const unsigned short* __restrict__ BT,
    const float* __restrict__ bias0, const float* __restrict__ bias1,
    void* __restrict__ out0, void* __restrict__ out1, void* __restrict__ out2,
    void* __restrict__ out3, int M, int N, int K) {
  __shared__ __align__(16) unsigned short SMEM[2 * 128 * 64];   // 32 KB: As | Bs, reused by epilogue
  unsigned short* As = SMEM;
  unsigned short* Bs = SMEM + 128 * 64;
  int tid = threadIdx.x, w = tid >> 6, lane = tid & 63;
  // XCD swizzle: bid%8 -> XCD (dispatch round-robin); per-XCD: 4 m-blocks x 24 n-blocks
  int bid = blockIdx.y * gridDim.x + blockIdx.x;   // 0..767
  int xcd = bid & 7, idx = bid >> 3;               // idx 0..95
  int m0 = (xcd * 4 + (idx & 3)) * 128;
  int n0 = (idx >> 2) * 128;
  int wm = w >> 1, wn = w & 1;
  f32x4 acc[4][4] = {};

  // staging: dest byte within region = i*4096 + w*1024 + lane*16 -> r = i*32+w*8+(lane>>3),
  // phys colb = (lane&7)*16; source elem col = ((lane&7)*16 ^ ((r&7)<<4))/2, r&7 = lane>>3
  int csrc = 8 * ((lane & 7) ^ (lane >> 3));       // pre-swizzled source column (elements)
  int rst  = w * 8 + (lane >> 3);                  // staging row base (+ i*32)
  // read-side swizzled fragment offset (elements): (ks*32 + (lane>>4)*8) ^ ((lane&7)<<3)
  int rxor = (lane & 7) << 3;

  for (int kt = 0; kt < (K >> 6); ++kt) {
#pragma unroll
    for (int i = 0; i < 4; ++i) {
      int r = i * 32 + rst;
      gload_lds16(A + (size_t)(m0 + r) * K + kt * 64 + csrc, As + i * 2048 + w * 512);
    }
#pragma unroll
    for (int i = 0; i < 4; ++i) {
      int r = i * 32 + rst;
      gload_lds16(BT + (size_t)(n0 + r) * K + kt * 64 + csrc, Bs + i * 2048 + w * 512);
    }
    __syncthreads();
#pragma unroll
    for (int ks = 0; ks < 2; ++ks) {
      int foff = (ks * 32 + (lane >> 4) * 8) ^ rxor;
      bf16x8 af[4], bfr[4];
#pragma unroll
      for (int mt = 0; mt < 4; ++mt)
        af[mt] = *(const bf16x8*)(As + (wm * 64 + mt * 16 + (lane & 15)) * 64 + foff);
#pragma unroll
      for (int nt = 0; nt < 4; ++nt)
        bfr[nt] = *(const bf16x8*)(Bs + (wn * 64 + nt * 16 + (lane & 15)) * 64 + foff);
#pragma unroll
      for (int mt = 0; mt < 4; ++mt)
#pragma unroll
        for (int nt = 0; nt < 4; ++nt)
          acc[mt][nt] = __builtin_amdgcn_mfma_f32_16x16x32_bf16(af[mt], bfr[nt], acc[mt][nt], 0, 0, 0);
    }
    __syncthreads();   // after this in the last iter, SMEM is dead -> epilogue may reuse
  }

  // ---- epilogue ----
  int nfirst = n0 + wn * 64;                 // wave's 64-wide n-range start (mult of 64)
  int region = nfirst >> 10;                 // wave-uniform
  unsigned short* eplds = SMEM + w * 4096;   // per-wave 64x64 ushort slice (8 KB)

#pragma unroll
  for (int mt = 0; mt < 4; ++mt) {
#pragma unroll
    for (int nt = 0; nt < 4; ++nt) {
      int n = nfirst + nt * 16 + (lane & 15);
      int tbase = m0 + wm * 64 + mt * 16 + (lane >> 4) * 4;
      float bb = (region < 2) ? bias0[n] : bias1[n - 2048];
      if (region <= 1) {
        // stage the [t][d] patch into LDS (XOR-swizzled cols, per-wave slice)
#pragma unroll
        for (int r = 0; r < 4; ++r) {
          int tl = mt * 16 + (lane >> 4) * 4 + r;          // 0..63 (row in patch)
          int col = nt * 16 + (lane & 15);                 // 0..63 (= d)
          eplds[tl * 64 + (col ^ ((tl & 7) << 3))] = f2bf(acc[mt][nt][r] + bb);
        }
        if (region == 1) {  // kT [bh][d][t] direct (t-contiguous)
          int h = (n >> 6) & 15, d = n & 63, b = tbase >> 11, t = tbase & 2047;
          ushort4 o;
          o.x = f2bf(acc[mt][nt][0] + bb);
          o.y = f2bf(acc[mt][nt][1] + bb);
          o.z = f2bf(acc[mt][nt][2] + bb);
          o.w = f2bf(acc[mt][nt][3] + bb);
          *(ushort4*)((unsigned short*)out2 + ((size_t)(b * Hh + h) * Hd + d) * Ss + t) = o;
        }
      } else {            // vT [bh][d][t] direct
        int h = (n >> 6) & 15, d = n & 63, b = tbase >> 11, t = tbase & 2047;
        ushort4 o;
        o.x = f2bf(acc[mt][nt][0] + bb);
        o.y = f2bf(acc[mt][nt][1] + bb);
        o.z = f2bf(acc[mt][nt][2] + bb);
        o.w = f2bf(acc[mt][nt][3] + bb);
        *(ushort4*)((unsigned short*)out3 + ((size_t)(b * Hh + h) * Hd + d) * Ss + t) = o;
      }
    }
  }
  if (region <= 1) {
    asm volatile("" ::: "memory");           // order LDS reads after writes (wave-private slice)
    int tl = lane;                           // one 128B row per lane
    int tt = m0 + wm * 64 + tl;
    int b = tt >> 11, t = tt & 2047;
    int h = (nfirst >> 6) & 15;
    unsigned short* dst = ((region == 0) ? (unsigned short*)out0 : (unsigned short*)out1)
                        + (((size_t)(b * Hh + h)) * Ss + t) * Hd;
#pragma unroll
    for (int c = 0; c < 8; ++c) {
      int col = (c * 8) ^ ((tl & 7) << 3);
      *(float4*)(dst + c * 8) = *(const float4*)(eplds + tl * 64 + col);
    }
  }
}

// ---------- output GEMM: 64x128 tile, 2-phase dbuf + XCD swizzle + T2 swizzle ----------
__global__ __launch_bounds__(256, 3) void k_gemm_o(
    const unsigned short* __restrict__ A, const unsigned short* __restrict__ BT,
    const float* __restrict__ bias, float* __restrict__ out) {
  constexpr int K = 1024, N = 1024;
  __shared__ __align__(16) unsigned short As[2][64 * 64];
  __shared__ __align__(16) unsigned short Bs[2][128 * 64];
  int tid = threadIdx.x, w = tid >> 6, lane = tid & 63;
  int bid = blockIdx.y * gridDim.x + blockIdx.x;   // 0..511
  int xcd = bid & 7, idx = bid >> 3;               // 0..63
  int m0 = (xcd * 8 + (idx & 7)) * 64;
  int n0 = (idx >> 3) * 128;
  int wm = w >> 1, wn = w & 1;
  f32x4 acc[2][4] = {};

  int csrc = 8 * ((lane & 7) ^ (lane >> 3));
  int rst  = w * 8 + (lane >> 3);
  int rxor = (lane & 7) << 3;

  auto STAGE = [&](int kt, int cur) {
#pragma unroll
    for (int i = 0; i < 2; ++i) {
      int r = i * 32 + rst;
      gload_lds16(A + (size_t)(m0 + r) * K + kt * 64 + csrc, As[cur] + i * 2048 + w * 512);
    }
#pragma unroll
    for (int i = 0; i < 4; ++i) {
      int r = i * 32 + rst;
      gload_lds16(BT + (size_t)(n0 + r) * K + kt * 64 + csrc, Bs[cur] + i * 2048 + w * 512);
    }
  };

  constexpr int NT = K >> 6;
  STAGE(0, 0);
  __syncthreads();
  for (int kt = 0; kt < NT; ++kt) {
    int cur = kt & 1;
    if (kt + 1 < NT) STAGE(kt + 1, cur ^ 1);
#pragma unroll
    for (int ks = 0; ks < 2; ++ks) {
      int foff = (ks * 32 + (lane >> 4) * 8) ^ rxor;
      bf16x8 af[2], bfr[4];
#pragma unroll
      for (int mt = 0; mt < 2; ++mt)
        af[mt] = *(const bf16x8*)(As[cur] + (wm * 32 + mt * 16 + (lane & 15)) * 64 + foff);
#pragma unroll
      for (int nt = 0; nt < 4; ++nt)
        bfr[nt] = *(const bf16x8*)(Bs[cur] + (wn * 64 + nt * 16 + (lane & 15)) * 64 + foff);
#pragma unroll
      for (int mt = 0; mt < 2; ++mt)
#pragma unroll
        for (int nt = 0; nt < 4; ++nt)
          acc[mt][nt] = __builtin_amdgcn_mfma_f32_16x16x32_bf16(af[mt], bfr[nt], acc[mt][nt], 0, 0, 0);
    }
    __syncthreads();
  }

#pragma unroll
  for (int mt = 0; mt < 2; ++mt) {
#pragma unroll
    for (int nt = 0; nt < 4; ++nt) {
      int n = n0 + wn * 64 + nt * 16 + (lane & 15);
      int m = m0 + wm * 32 + mt * 16 + (lane >> 4) * 4;
      float bb = bias[n];
#pragma unroll
      for (int r = 0; r < 4; ++r)
        out[(size_t)(m + r) * N + n] = acc[mt][nt][r] + bb;
    }
  }
}

// ---------- pass A1: per-chunk gram ----------
__global__ __launch_bounds__(64) void k_gram(
    const unsigned short* __restrict__ vT, const unsigned short* __restrict__ kT,
    unsigned short* __restrict__ G) {
  int lane = threadIdx.x;
  int j = blockIdx.x, bh = blockIdx.y;
  int t0 = j * 64;
  const unsigned short* vb = vT + (size_t)bh * Hd * Ss;
  const unsigned short* kb = kT + (size_t)bh * Hd * Ss;
  unsigned short* g = G + ((size_t)bh * NCH + j) * 4096;

  bf16x8 af[4][2], bfr[4][2];
#pragma unroll
  for (int mt = 0; mt < 4; ++mt)
#pragma unroll
    for (int ks = 0; ks < 2; ++ks) {
      af[mt][ks]  = *(const bf16x8*)(vb + (size_t)(mt * 16 + (lane & 15)) * Ss + t0 + ks * 32 + (lane >> 4) * 8);
      bfr[mt][ks] = *(const bf16x8*)(kb + (size_t)(mt * 16 + (lane & 15)) * Ss + t0 + ks * 32 + (lane >> 4) * 8);
    }
  f32x4 acc[4][4] = {};
#pragma unroll
  for (int mt = 0; mt < 4; ++mt)
#pragma unroll
    for (int nt = 0; nt < 4; ++nt)
#pragma unroll
      for (int ks = 0; ks < 2; ++ks)
        acc[mt][nt] = __builtin_amdgcn_mfma_f32_16x16x32_bf16(af[mt][ks], bfr[nt][ks], acc[mt][nt], 0, 0, 0);
#pragma unroll
  for (int mt = 0; mt < 4; ++mt)
#pragma unroll
    for (int nt = 0; nt < 4; ++nt)
#pragma unroll
      for (int r = 0; r < 4; ++r)
        g[(mt * 16 + (lane >> 4) * 4 + r) * 64 + nt * 16 + (lane & 15)] = f2bf(acc[mt][nt][r]);
}

// ---------- pass A2: exclusive prefix over chunks ----------
__global__ __launch_bounds__(256) void k_prefix(
    const unsigned short* __restrict__ G, unsigned short* __restrict__ Sp) {
  int gidx = blockIdx.x * 256 + threadIdx.x;   // 32 bh * 4096 elems
  int bh = gidx >> 12, e = gidx & 4095;
  const unsigned short* gp = G + (size_t)bh * NCH * 4096 + e;
  unsigned short* sp = Sp + (size_t)bh * NCH * 4096 + e;
  float acc = 0.f;
#pragma unroll
  for (int j = 0; j < NCH; ++j) {
    sp[(size_t)j * 4096] = f2bf(acc);
    acc += bf2f(gp[(size_t)j * 4096]);
  }
}

// ---------- pass B: per-chunk attention ----------
__global__ __launch_bounds__(256, 6) void k_chunk_attn(
    const unsigned short* __restrict__ q, const unsigned short* __restrict__ k,
    const unsigned short* __restrict__ vT, const unsigned short* __restrict__ Sp,
    const float* __restrict__ invn, unsigned short* __restrict__ ctx) {
  __shared__ __align__(16) unsigned short P[4 * 16 * 64];
  int tid = threadIdx.x, w = tid >> 6, lane = tid & 63;
  int j = blockIdx.x, bh = blockIdx.y;
  int t0 = j * 64;
  const unsigned short* qb = q + (size_t)bh * Ss * Hd;
  const unsigned short* kb = k + (size_t)bh * Ss * Hd;
  const unsigned short* vb = vT + (size_t)bh * Hd * Ss;
  const unsigned short* sp = Sp + ((size_t)bh * NCH + j) * 4096;

  bf16x8 qf[2];
#pragma unroll
  for (int ks = 0; ks < 2; ++ks)
    qf[ks] = *(const bf16x8*)(qb + (size_t)(t0 + w * 16 + (lane & 15)) * Hd + ks * 32 + (lane >> 4) * 8);

  f32x4 acc[4] = {};
#pragma unroll
  for (int nt = 0; nt < 4; ++nt)
#pragma unroll
    for (int ks = 0; ks < 2; ++ks) {
      bf16x8 sf = *(const bf16x8*)(sp + (nt * 16 + (lane & 15)) * 64 + ks * 32 + (lane >> 4) * 8);
      acc[nt] = __builtin_amdgcn_mfma_f32_16x16x32_bf16(qf[ks], sf, acc[nt], 0, 0, 0);
    }

  f32x4 sacc[4] = {};
#pragma unroll
  for (int nt = 0; nt < 4; ++nt)
#pragma unroll
    for (int ks = 0; ks < 2; ++ks) {
      bf16x8 kf = *(const bf16x8*)(kb + (size_t)(t0 + nt * 16 + (lane & 15)) * Hd + ks * 32 + (lane >> 4) * 8);
      sacc[nt] = __builtin_amdgcn_mfma_f32_16x16x32_bf16(qf[ks], kf, sacc[nt], 0, 0, 0);
    }

#pragma unroll
  for (int nt = 0; nt < 4; ++nt)
#pragma unroll
    for (int r = 0; r < 4; ++r) {
      int row = (lane >> 4) * 4 + r;
      int s_local = nt * 16 + (lane & 15);
      float vv = (s_local <= w * 16 + row) ? sacc[nt][r] : 0.f;
      int cb = s_local * 2;
      int byte = w * 2048 + row * 128 + (cb ^ ((row & 7) << 4));
      *(unsigned short*)((char*)P + byte) = f2bf(vv);
    }
  asm volatile("" ::: "memory");

  bf16x8 pf[2];
#pragma unroll
  for (int ks = 0; ks < 2; ++ks) {
    int prow = lane & 15;
    int pcb = (ks * 32 + (lane >> 4) * 8) * 2;
    pf[ks] = *(const bf16x8*)((char*)P + w * 2048 + prow * 128 + (pcb ^ ((prow & 7) << 4)));
  }
#pragma unroll
  for (int dt = 0; dt < 4; ++dt)
#pragma unroll
    for (int ks = 0; ks < 2; ++ks) {
      bf16x8 vf = *(const bf16x8*)(vb + (size_t)(dt * 16 + (lane & 15)) * Ss + t0 + ks * 32 + (lane >> 4) * 8);
      acc[dt] = __builtin_amdgcn_mfma_f32_16x16x32_bf16(pf[ks], vf, acc[dt], 0, 0, 0);
    }

  int b = bh >> 4, h = bh & 15;
  float sc[4];
#pragma unroll
  for (int r = 0; r < 4; ++r)
    sc[r] = invn[(size_t)bh * Ss + t0 + w * 16 + (lane >> 4) * 4 + r];
#pragma unroll
  for (int dt = 0; dt < 4; ++dt)
#pragma unroll
    for (int r = 0; r < 4; ++r) {
      int t = t0 + w * 16 + (lane >> 4) * 4 + r;
      size_t m = (size_t)b * Ss + t;
      ctx[m * Dm + h * Hd + dt * 16 + (lane & 15)] = f2bf(acc[dt][r] * sc[r]);
    }
}

// ---------- launch ----------
extern "C" void kernel_launch(void* const* d_in, const int* in_sizes, int n_in,
                              void* d_out, int out_size, void* d_ws, size_t ws_size,
                              hipStream_t stream) {
  const float* x   = (const float*)d_in[0];
  const float* Wqk = (const float*)d_in[1];
  const float* bqk = (const float*)d_in[2];
  const float* Wv  = (const float*)d_in[3];
  const float* bv  = (const float*)d_in[4];
  const float* Wn  = (const float*)d_in[5];
  const float* bn  = (const float*)d_in[6];
  const float* Wo  = (const float*)d_in[7];
  const float* bo  = (const float*)d_in[8];

  char* ws = (char*)d_ws;
  size_t off = 0;
  unsigned short* xb    = (unsigned short*)(ws + off); off += (size_t)Mtot * Dm * 2;          // 8 MB
  unsigned short* wprojT= (unsigned short*)(ws + off); off += (size_t)3072 * 1024 * 2;        // 6 MB
  unsigned short* woT   = (unsigned short*)(ws + off); off += (size_t)1024 * 1024 * 2;        // 2 MB
  unsigned short* qbuf  = (unsigned short*)(ws + off); off += (size_t)Bb * Hh * Ss * Hd * 2;  // 8 MB
  unsigned short* kbuf  = (unsigned short*)(ws + off); off += (size_t)Bb * Hh * Ss * Hd * 2;  // 8 MB
  unsigned short* ktbuf = (unsigned short*)(ws + off); off += (size_t)Bb * Hh * Ss * Hd * 2;  // 8 MB
  unsigned short* vbuf  = (unsigned short*)(ws + off); off += (size_t)Bb * Hh * Ss * Hd * 2;  // 8 MB
  float* invn           = (float*)(ws + off);          off += (size_t)Bb * Hh * Ss * 4;       // 256 KB
  unsigned short* G     = (unsigned short*)(ws + off); off += (size_t)Bb * Hh * NCH * 4096 * 2; // 8 MB
  unsigned short* Sp    = (unsigned short*)(ws + off); off += (size_t)Bb * Hh * NCH * 4096 * 2; // 8 MB
  unsigned short* ctx   = xb;  // alias: xb dead after fused projection GEMM

  // 1) fused prep (one launch)
  k_prep<<<5120, 256, 0, stream>>>(x, Wn, bn, invn, xb, Wqk, Wv, Wo, wprojT, woT);

  // 2) fused q/k/v projections (N = 3072), m97 + XCD swizzle + T2 swizzle (768 blocks)
  k_gemm_proj<<<dim3(3072 / 128, Mtot / 128), 256, 0, stream>>>(
      xb, wprojT, bqk, bv, qbuf, kbuf, ktbuf, vbuf, Mtot, 3072, 1024);

  // 3) attention = parallel gram + parallel prefix + per-chunk
  k_gram<<<dim3(NCH, Bb * Hh), 64, 0, stream>>>(vbuf, ktbuf, G);
  k_prefix<<<(Bb * Hh * 4096) / 256, 256, 0, stream>>>(G, Sp);
  k_chunk_attn<<<dim3(NCH, Bb * Hh), 256, 0, stream>>>(qbuf, kbuf, vbuf, Sp, invn, ctx);

  // 4) output projection -> f32 d_out, 64x128 2-phase dbuf + XCD + T2 swizzle (512 blocks)
  k_gemm_o<<<dim3(1024 / 128, Mtot / 64), 256, 0, stream>>>(ctx, woT, bo, (float*)d_out);
}